// Round 11
// baseline (153.345 us; speedup 1.0000x reference)
//
#include <hip/hip_runtime.h>

// GAT attention scores, R19: R18 + finer ranges (fill all 256 CUs in
// node_sort) + int4 second pass in bin_scatter.
//
// Measured cost-model (R8-R18):
//  - fp32 LDS atomicAdd per edge: POISON (~88us/12.8M) [R12]
//  - random 16B gathers into L2-resident tables: CHEAP (~20us/stream) [R13]
//  - scattered sub-line stores: ~1 line-writeback each UNLESS the block
//    owns the destination window (single-owner => full lines) [R15/R16]
//  - int atomics (LDS / global non-returning / 78K returning): cheap
//  - under-filled or single-block launches: 1-CU serialization [R14];
//    196 blocks on 256 CUs leaves 25% idle -> RSH 8->7 (NR=391).
//
// Pipeline (5 dispatches): node_proj (+rcur=0) -> bin_scatter (LDS sort,
//  self-allocating fixed-CAP segments) -> node_sort (single-owner sc2col,
//  391 blocks) -> accum (8 lanes/node, atomic-free) -> edge_out.
//
// ws (~14.9MB < 15.82 proven): s2h .8M | combh 1.6M | binned 8.0M |
//   sc2col 4.0M | nstart .2M | ncnt .2M | rcur 1.6K

constexpr int NN = 50000;
constexpr int NE = 1600000;
constexpr int F  = 32;
constexpr int H  = 8;
constexpr float ALPHA = 0.2f;
constexpr float EPS   = 1e-12f;

constexpr int RSH     = 7;
constexpr int RNODES  = 1 << RSH;                   // 128 nodes/range
constexpr int NR      = (NN + RNODES - 1) / RNODES; // 391
constexpr int NB      = 400;                        // blocks in scatter pass
constexpr int CHUNK   = NE / NB;                    // 4000 edges/block
constexpr int CAP     = 5120;                       // per-range capacity
                                                    // (mean 4092, sigma~64)

typedef _Float16 v8h __attribute__((ext_vector_type(8)));

__global__ __launch_bounds__(256) void node_proj_kernel(
    const float* __restrict__ x, const float* __restrict__ aa,
    float* __restrict__ combh, float* __restrict__ s2h,
    int* __restrict__ rcur)
{
    __shared__ float aal[H * 2 * F];
    for (int i = threadIdx.x; i < H * 2 * F; i += 256) aal[i] = aa[i];
    __syncthreads();

    int n = blockIdx.x * 256 + threadIdx.x;
    if (n < NR) rcur[n] = 0;                       // zero range cursors
    if (n >= NN) return;

    const float4* xp = reinterpret_cast<const float4*>(x + (size_t)n * F);
    float4 xv[F / 4];
#pragma unroll
    for (int i = 0; i < F / 4; ++i) xv[i] = xp[i];

    float o1[H], o2[H];
#pragma unroll
    for (int h = 0; h < H; ++h) {
        const float* a1 = &aal[h * 2 * F];
        const float* a2 = a1 + F;
        float acc1 = 0.f, acc2 = 0.f;
#pragma unroll
        for (int i = 0; i < F / 4; ++i) {
            acc1 = fmaf(a1[4*i+0], xv[i].x, acc1);
            acc1 = fmaf(a1[4*i+1], xv[i].y, acc1);
            acc1 = fmaf(a1[4*i+2], xv[i].z, acc1);
            acc1 = fmaf(a1[4*i+3], xv[i].w, acc1);
            acc2 = fmaf(a2[4*i+0], xv[i].x, acc2);
            acc2 = fmaf(a2[4*i+1], xv[i].y, acc2);
            acc2 = fmaf(a2[4*i+2], xv[i].z, acc2);
            acc2 = fmaf(a2[4*i+3], xv[i].w, acc2);
        }
        o1[h] = acc1; o2[h] = acc2;
    }

    v8h s1v, s2v;
#pragma unroll
    for (int h = 0; h < H; ++h) { s1v[h] = (_Float16)o1[h]; s2v[h] = (_Float16)o2[h]; }
    reinterpret_cast<v8h*>(combh)[(size_t)n * 2] = s1v;   // lnrech slot filled later
    reinterpret_cast<v8h*>(s2h)[n] = s2v;
}

// in-LDS counting sort by range; claim global slots via returning atomic
// (1 per nonempty (block,range)); run-wise writeout into fixed segments.
__global__ __launch_bounds__(256) void bin_scatter_kernel(
    const int* __restrict__ row, const int* __restrict__ col,
    int* __restrict__ rcur, unsigned* __restrict__ binned)
{
    __shared__ unsigned vals[CHUNK];   // 16 KB locally sorted (r<<16|c)
    __shared__ int hist[NR];
    __shared__ int lstart[NR];
    __shared__ int cursor[NR];
    __shared__ int gbase[NR];

    const int t = threadIdx.x;
    for (int i = t; i < NR; i += 256) hist[i] = 0;
    __syncthreads();

    const int base = blockIdx.x * CHUNK;
    const int4* r4 = reinterpret_cast<const int4*>(row + base);
    const int4* c4 = reinterpret_cast<const int4*>(col + base);
    for (int i = t; i < CHUNK / 4; i += 256) {
        int4 r = r4[i];
        atomicAdd(&hist[r.x >> RSH], 1);
        atomicAdd(&hist[r.y >> RSH], 1);
        atomicAdd(&hist[r.z >> RSH], 1);
        atomicAdd(&hist[r.w >> RSH], 1);
    }
    __syncthreads();

    if (t == 0) {
        int run = 0;
        for (int r = 0; r < NR; ++r) {
            lstart[r] = run;
            cursor[r] = run;
            run += hist[r];
        }
    }
    __syncthreads();

    // claim per-range global slots (returning atomics, ~78K total pipeline)
    for (int r = t; r < NR; r += 256)
        gbase[r] = (hist[r] > 0) ? atomicAdd(&rcur[r], hist[r]) : 0;

    for (int i = t; i < CHUNK / 4; i += 256) {
        int4 r = r4[i], c = c4[i];
        int rr[4] = {r.x, r.y, r.z, r.w};
        int cc[4] = {c.x, c.y, c.z, c.w};
#pragma unroll
        for (int k = 0; k < 4; ++k) {
            int pos = atomicAdd(&cursor[rr[k] >> RSH], 1);
            vals[pos] = ((unsigned)rr[k] << 16) | (unsigned)cc[k];
        }
    }
    __syncthreads();

    for (int j = t; j < CHUNK; j += 256) {
        unsigned v = vals[j];
        int rg = (int)(v >> (16 + RSH));
        binned[(size_t)rg * CAP + gbase[rg] + (j - lstart[rg])] = v;
    }
}

// 391 blocks (fills all CUs): per-range node counting sort. sc2col segment
// is SINGLE-OWNER (this block) -> full-line writebacks, no amplification.
__global__ __launch_bounds__(512) void node_sort_kernel(
    const unsigned* __restrict__ binned, const int* __restrict__ rcur,
    int* __restrict__ nstart, int* __restrict__ ncnt,
    unsigned short* __restrict__ sc2col)
{
    __shared__ int cnt[RNODES];
    __shared__ int cur[RNODES];
    const int rx = blockIdx.x;
    const int rbase = rx << RSH;
    const int rb = rx * CAP, re = rb + rcur[rx];
    const int t = threadIdx.x;

    if (t < RNODES) cnt[t] = 0;
    __syncthreads();
    for (int i = rb + t; i < re; i += 512) {
        unsigned d = (binned[i] >> 16) - (unsigned)rbase;
        atomicAdd(&cnt[d], 1);           // all entries valid (no sentinels)
    }
    __syncthreads();
    if (t == 0) {
        int run = rb;
        for (int d = 0; d < RNODES; ++d) { cur[d] = run; run += cnt[d]; }
    }
    __syncthreads();
    if (t < RNODES) {
        int n = rbase + t;
        if (n < NN) { nstart[n] = cur[t]; ncnt[n] = cnt[t]; }
    }
    __syncthreads();                     // nstart reads done before cur mutates
    for (int i = rb + t; i < re; i += 512) {
        unsigned v = binned[i];
        unsigned d = (v >> 16) - (unsigned)rbase;
        int pos = atomicAdd(&cur[d], 1);
        sc2col[pos] = (unsigned short)(v & 0xFFFFu);   // single-owner window
    }
}

// atomic-free accumulation: 8 lanes/node; contiguous sc2col reads, one
// random s2 gather per edge (L2-resident, proven-cheap), fp32 exp,
// 3-round shfl_xor reduce, lane 0 writes lnrec.
__global__ __launch_bounds__(256) void accum_kernel(
    const int* __restrict__ nstart, const int* __restrict__ ncnt,
    const unsigned short* __restrict__ sc2col,
    const float* __restrict__ s2h, float* __restrict__ combh)
{
    int n = blockIdx.x * 32 + (threadIdx.x >> 3);
    int lane = threadIdx.x & 7;
    if (n >= NN) return;
    const v8h* combv = reinterpret_cast<const v8h*>(combh);
    const v8h* s2v   = reinterpret_cast<const v8h*>(s2h);

    v8h a = combv[(size_t)n * 2];
    const int b = nstart[n], c = ncnt[n];

    float s[H];
#pragma unroll
    for (int h = 0; h < H; ++h) s[h] = 0.f;

    for (int j = lane; j < c; j += 8) {
        unsigned cl = sc2col[b + j];
        v8h bb = s2v[cl];
#pragma unroll
        for (int h = 0; h < H; ++h) {
            float t = (float)a[h] + (float)bb[h];
            t = fmaxf(t, ALPHA * t);
            s[h] += __expf(t);
        }
    }
#pragma unroll
    for (int h = 0; h < H; ++h) {
        s[h] += __shfl_xor(s[h], 1);
        s[h] += __shfl_xor(s[h], 2);
        s[h] += __shfl_xor(s[h], 4);
    }
    if (lane == 0) {
        v8h lnh;
#pragma unroll
        for (int h = 0; h < H; ++h) lnh[h] = (_Float16)(-__logf(s[h] + EPS));
        reinterpret_cast<v8h*>(combh)[(size_t)n * 2 + 1] = lnh;
    }
}

// eid-order: 4 edges/thread; 2 random gather streams (proven-cheap);
// coalesced float4 stores per h-plane.
__global__ __launch_bounds__(256) void edge_out_kernel(
    const int* __restrict__ row, const int* __restrict__ col,
    const float* __restrict__ combh, const float* __restrict__ s2h,
    float* __restrict__ out)
{
    int e0 = (blockIdx.x * 256 + threadIdx.x) * 4;
    if (e0 >= NE) return;
    int4 r4 = *reinterpret_cast<const int4*>(row + e0);
    int4 c4 = *reinterpret_cast<const int4*>(col + e0);
    int rr[4] = {r4.x, r4.y, r4.z, r4.w};
    int cc[4] = {c4.x, c4.y, c4.z, c4.w};
    const v8h* combv = reinterpret_cast<const v8h*>(combh);
    const v8h* s2v   = reinterpret_cast<const v8h*>(s2h);

    float res[4][H];
#pragma unroll
    for (int k = 0; k < 4; ++k) {
        v8h a  = combv[(size_t)rr[k] * 2];
        v8h ln = combv[(size_t)rr[k] * 2 + 1];
        v8h b  = s2v[cc[k]];
#pragma unroll
        for (int h = 0; h < H; ++h) {
            float t = (float)a[h] + (float)b[h];
            t = fmaxf(t, ALPHA * t);
            res[k][h] = __expf(t + (float)ln[h]);   // == exp(leaky(t)) / (sum+eps)
        }
    }
#pragma unroll
    for (int h = 0; h < H; ++h) {
        *reinterpret_cast<float4*>(out + (size_t)h * NE + e0) =
            make_float4(res[0][h], res[1][h], res[2][h], res[3][h]);
    }
}

extern "C" void kernel_launch(void* const* d_in, const int* in_sizes, int n_in,
                              void* d_out, int out_size, void* d_ws, size_t ws_size,
                              hipStream_t stream) {
    const float* x   = (const float*)d_in[0];
    const float* aa  = (const float*)d_in[1];
    const int*   row = (const int*)d_in[2];
    const int*   col = (const int*)d_in[3];
    float* out = (float*)d_out;

    // ws (~14.9 MB)
    float* s2h   = (float*)d_ws;                              // NN*4 floats
    float* combh = s2h + (size_t)NN * 4;                      // NN*8 floats
    unsigned* binned = (unsigned*)(combh + (size_t)NN * 8);   // NR*CAP uints
    unsigned short* sc2col = (unsigned short*)(binned + (size_t)NR * CAP); // NR*CAP
    int* nstart  = (int*)(sc2col + (size_t)NR * CAP);         // NN
    int* ncnt    = nstart + NN;                               // NN
    int* rcur    = ncnt + NN;                                 // NR

    node_proj_kernel<<<(NN + 255) / 256, 256, 0, stream>>>(x, aa, combh, s2h, rcur);
    bin_scatter_kernel<<<NB, 256, 0, stream>>>(row, col, rcur, binned);
    node_sort_kernel<<<NR, 512, 0, stream>>>(binned, rcur, nstart, ncnt, sc2col);
    accum_kernel<<<(NN * 8 + 255) / 256, 256, 0, stream>>>(nstart, ncnt, sc2col, s2h, combh);
    edge_out_kernel<<<(NE / 4 + 255) / 256, 256, 0, stream>>>(row, col, combh, s2h, out);
}

// Round 12
// 144.064 us; speedup vs baseline: 1.0644x; 1.0644x over previous
//
#include <hip/hip_runtime.h>

// GAT attention scores, R20: fuse node_sort+accum (sorted col list stays
// in LDS; sc2col/nstart/ncnt deleted; 5 -> 4 dispatches).
//
// Measured cost-model (R8-R19):
//  - fp32 LDS atomicAdd per edge: POISON (~88us/12.8M) [R12]
//  - random 16B gathers into L2-resident tables: CHEAP (~20us/stream) [R13]
//  - scattered sub-line stores: ~1 line-writeback each UNLESS the block
//    owns the destination window (single-owner => full lines) [R15/R16]
//  - int atomics (LDS / global non-returning / 78K returning): cheap
//  - single-block / under-filled launches: 1-CU serialization [R14]
//  - R19 (RSH 7, int4 pass): neutral - kernels at class floors.
//
// Pipeline (4 dispatches): node_proj (+rcur=0) -> bin_scatter (LDS sort,
//  self-allocating fixed-CAP segments) -> node_sort_accum (counting sort
//  into LDS, then 4 lanes/node segment-sum exp from LDS; s2 gathers
//  global; writes lnrec directly) -> edge_out (eid-order).
//
// ws (~10.4MB): s2h .8M | combh 1.6M | binned 8.0M | rcur 1.6K

constexpr int NN = 50000;
constexpr int NE = 1600000;
constexpr int F  = 32;
constexpr int H  = 8;
constexpr float ALPHA = 0.2f;
constexpr float EPS   = 1e-12f;

constexpr int RSH     = 7;
constexpr int RNODES  = 1 << RSH;                   // 128 nodes/range
constexpr int NR      = (NN + RNODES - 1) / RNODES; // 391
constexpr int NB      = 400;                        // blocks in scatter pass
constexpr int CHUNK   = NE / NB;                    // 4000 edges/block
constexpr int CAP     = 5120;                       // per-range capacity
                                                    // (mean 4092, sigma~64)

typedef _Float16 v8h __attribute__((ext_vector_type(8)));

__global__ __launch_bounds__(256) void node_proj_kernel(
    const float* __restrict__ x, const float* __restrict__ aa,
    float* __restrict__ combh, float* __restrict__ s2h,
    int* __restrict__ rcur)
{
    __shared__ float aal[H * 2 * F];
    for (int i = threadIdx.x; i < H * 2 * F; i += 256) aal[i] = aa[i];
    __syncthreads();

    int n = blockIdx.x * 256 + threadIdx.x;
    if (n < NR) rcur[n] = 0;                       // zero range cursors
    if (n >= NN) return;

    const float4* xp = reinterpret_cast<const float4*>(x + (size_t)n * F);
    float4 xv[F / 4];
#pragma unroll
    for (int i = 0; i < F / 4; ++i) xv[i] = xp[i];

    float o1[H], o2[H];
#pragma unroll
    for (int h = 0; h < H; ++h) {
        const float* a1 = &aal[h * 2 * F];
        const float* a2 = a1 + F;
        float acc1 = 0.f, acc2 = 0.f;
#pragma unroll
        for (int i = 0; i < F / 4; ++i) {
            acc1 = fmaf(a1[4*i+0], xv[i].x, acc1);
            acc1 = fmaf(a1[4*i+1], xv[i].y, acc1);
            acc1 = fmaf(a1[4*i+2], xv[i].z, acc1);
            acc1 = fmaf(a1[4*i+3], xv[i].w, acc1);
            acc2 = fmaf(a2[4*i+0], xv[i].x, acc2);
            acc2 = fmaf(a2[4*i+1], xv[i].y, acc2);
            acc2 = fmaf(a2[4*i+2], xv[i].z, acc2);
            acc2 = fmaf(a2[4*i+3], xv[i].w, acc2);
        }
        o1[h] = acc1; o2[h] = acc2;
    }

    v8h s1v, s2v;
#pragma unroll
    for (int h = 0; h < H; ++h) { s1v[h] = (_Float16)o1[h]; s2v[h] = (_Float16)o2[h]; }
    reinterpret_cast<v8h*>(combh)[(size_t)n * 2] = s1v;   // lnrech slot filled later
    reinterpret_cast<v8h*>(s2h)[n] = s2v;
}

// in-LDS counting sort by range; claim global slots via returning atomic
// (1 per nonempty (block,range)); run-wise writeout into fixed segments.
__global__ __launch_bounds__(256) void bin_scatter_kernel(
    const int* __restrict__ row, const int* __restrict__ col,
    int* __restrict__ rcur, unsigned* __restrict__ binned)
{
    __shared__ unsigned vals[CHUNK];   // 16 KB locally sorted (r<<16|c)
    __shared__ int hist[NR];
    __shared__ int lstart[NR];
    __shared__ int cursor[NR];
    __shared__ int gbase[NR];

    const int t = threadIdx.x;
    for (int i = t; i < NR; i += 256) hist[i] = 0;
    __syncthreads();

    const int base = blockIdx.x * CHUNK;
    const int4* r4 = reinterpret_cast<const int4*>(row + base);
    const int4* c4 = reinterpret_cast<const int4*>(col + base);
    for (int i = t; i < CHUNK / 4; i += 256) {
        int4 r = r4[i];
        atomicAdd(&hist[r.x >> RSH], 1);
        atomicAdd(&hist[r.y >> RSH], 1);
        atomicAdd(&hist[r.z >> RSH], 1);
        atomicAdd(&hist[r.w >> RSH], 1);
    }
    __syncthreads();

    if (t == 0) {
        int run = 0;
        for (int r = 0; r < NR; ++r) {
            lstart[r] = run;
            cursor[r] = run;
            run += hist[r];
        }
    }
    __syncthreads();

    // claim per-range global slots (returning atomics, ~78K total pipeline)
    for (int r = t; r < NR; r += 256)
        gbase[r] = (hist[r] > 0) ? atomicAdd(&rcur[r], hist[r]) : 0;

    for (int i = t; i < CHUNK / 4; i += 256) {
        int4 r = r4[i], c = c4[i];
        int rr[4] = {r.x, r.y, r.z, r.w};
        int cc[4] = {c.x, c.y, c.z, c.w};
#pragma unroll
        for (int k = 0; k < 4; ++k) {
            int pos = atomicAdd(&cursor[rr[k] >> RSH], 1);
            vals[pos] = ((unsigned)rr[k] << 16) | (unsigned)cc[k];
        }
    }
    __syncthreads();

    for (int j = t; j < CHUNK; j += 256) {
        unsigned v = vals[j];
        int rg = (int)(v >> (16 + RSH));
        binned[(size_t)rg * CAP + gbase[rg] + (j - lstart[rg])] = v;
    }
}

// 391 blocks: per-range counting sort INTO LDS, then fused atomic-free
// accumulation (4 lanes/node, segment sums from LDS, global s2 gathers -
// proven-cheap class). Writes lnrec directly. No global intermediates.
__global__ __launch_bounds__(512) void node_sort_accum_kernel(
    const unsigned* __restrict__ binned, const int* __restrict__ rcur,
    const float* __restrict__ s2h, float* __restrict__ combh)
{
    __shared__ int cnt[RNODES];
    __shared__ int cur[RNODES];
    __shared__ int nst[RNODES];
    __shared__ unsigned short scol[CAP];   // 10 KB sorted cols (range-local)
    const int rx = blockIdx.x;
    const int rbase = rx << RSH;
    const int rb = rx * CAP, re = rb + rcur[rx];
    const int t = threadIdx.x;

    if (t < RNODES) cnt[t] = 0;
    __syncthreads();
    for (int i = rb + t; i < re; i += 512) {
        unsigned d = (binned[i] >> 16) - (unsigned)rbase;
        atomicAdd(&cnt[d], 1);           // all entries valid (no sentinels)
    }
    __syncthreads();
    if (t == 0) {
        int run = 0;
        for (int d = 0; d < RNODES; ++d) { cur[d] = run; run += cnt[d]; }
    }
    __syncthreads();
    if (t < RNODES) nst[t] = cur[t];     // save segment starts
    __syncthreads();
    for (int i = rb + t; i < re; i += 512) {   // second binned pass: L2-hit
        unsigned v = binned[i];
        unsigned d = (v >> 16) - (unsigned)rbase;
        int pos = atomicAdd(&cur[d], 1);
        scol[pos] = (unsigned short)(v & 0xFFFFu);
    }
    __syncthreads();

    // fused accum: 4 contiguous lanes per node (512 thr / 128 nodes).
    // shfl groups are wave-aligned (4 | 64).
    const int d = t >> 2;
    const int lane = t & 3;
    const int n = rbase + d;
    if (n >= NN) return;
    const v8h* combv = reinterpret_cast<const v8h*>(combh);
    const v8h* s2v   = reinterpret_cast<const v8h*>(s2h);

    v8h a = combv[(size_t)n * 2];
    const int b0 = nst[d], c = cnt[d];

    float s[H];
#pragma unroll
    for (int h = 0; h < H; ++h) s[h] = 0.f;

    for (int j = lane; j < c; j += 4) {
        unsigned cl = scol[b0 + j];
        v8h bb = s2v[cl];
#pragma unroll
        for (int h = 0; h < H; ++h) {
            float tt = (float)a[h] + (float)bb[h];
            tt = fmaxf(tt, ALPHA * tt);
            s[h] += __expf(tt);
        }
    }
#pragma unroll
    for (int h = 0; h < H; ++h) {
        s[h] += __shfl_xor(s[h], 1);
        s[h] += __shfl_xor(s[h], 2);
    }
    if (lane == 0) {
        v8h lnh;
#pragma unroll
        for (int h = 0; h < H; ++h) lnh[h] = (_Float16)(-__logf(s[h] + EPS));
        reinterpret_cast<v8h*>(combh)[(size_t)n * 2 + 1] = lnh;
    }
}

// eid-order: 4 edges/thread; 2 random gather streams (proven-cheap);
// coalesced float4 stores per h-plane.
__global__ __launch_bounds__(256) void edge_out_kernel(
    const int* __restrict__ row, const int* __restrict__ col,
    const float* __restrict__ combh, const float* __restrict__ s2h,
    float* __restrict__ out)
{
    int e0 = (blockIdx.x * 256 + threadIdx.x) * 4;
    if (e0 >= NE) return;
    int4 r4 = *reinterpret_cast<const int4*>(row + e0);
    int4 c4 = *reinterpret_cast<const int4*>(col + e0);
    int rr[4] = {r4.x, r4.y, r4.z, r4.w};
    int cc[4] = {c4.x, c4.y, c4.z, c4.w};
    const v8h* combv = reinterpret_cast<const v8h*>(combh);
    const v8h* s2v   = reinterpret_cast<const v8h*>(s2h);

    float res[4][H];
#pragma unroll
    for (int k = 0; k < 4; ++k) {
        v8h a  = combv[(size_t)rr[k] * 2];
        v8h ln = combv[(size_t)rr[k] * 2 + 1];
        v8h b  = s2v[cc[k]];
#pragma unroll
        for (int h = 0; h < H; ++h) {
            float t = (float)a[h] + (float)b[h];
            t = fmaxf(t, ALPHA * t);
            res[k][h] = __expf(t + (float)ln[h]);   // == exp(leaky(t)) / (sum+eps)
        }
    }
#pragma unroll
    for (int h = 0; h < H; ++h) {
        *reinterpret_cast<float4*>(out + (size_t)h * NE + e0) =
            make_float4(res[0][h], res[1][h], res[2][h], res[3][h]);
    }
}

extern "C" void kernel_launch(void* const* d_in, const int* in_sizes, int n_in,
                              void* d_out, int out_size, void* d_ws, size_t ws_size,
                              hipStream_t stream) {
    const float* x   = (const float*)d_in[0];
    const float* aa  = (const float*)d_in[1];
    const int*   row = (const int*)d_in[2];
    const int*   col = (const int*)d_in[3];
    float* out = (float*)d_out;

    // ws (~10.4 MB)
    float* s2h   = (float*)d_ws;                              // NN*4 floats
    float* combh = s2h + (size_t)NN * 4;                      // NN*8 floats
    unsigned* binned = (unsigned*)(combh + (size_t)NN * 8);   // NR*CAP uints
    int* rcur    = (int*)(binned + (size_t)NR * CAP);         // NR

    node_proj_kernel<<<(NN + 255) / 256, 256, 0, stream>>>(x, aa, combh, s2h, rcur);
    bin_scatter_kernel<<<NB, 256, 0, stream>>>(row, col, rcur, binned);
    node_sort_accum_kernel<<<NR, 512, 0, stream>>>(binned, rcur, s2h, combh);
    edge_out_kernel<<<(NE / 4 + 255) / 256, 256, 0, stream>>>(row, col, combh, s2h, out);
}